// Round 10
// baseline (275.094 us; speedup 1.0000x reference)
//
#include <hip/hip_runtime.h>

#define N_NODES 50000
#define N_EDGES 800000
#define BUCKETS 196   // ceil(N_NODES / 256)
#define ECHUNK 4096
#define EBLKS 196     // ceil(N_EDGES / ECHUNK)
#define BCAP 5120     // bucket capacity; mean 4096, sigma 64 -> 16 sigma headroom

typedef __attribute__((ext_vector_type(8))) _Float16 half8;
typedef __attribute__((ext_vector_type(4))) float f32x4;

// ---------------- fused prep: binscatter (196) + wprep (32) + xcast (3125) ----------------
// Bucket b = dst >> 8. Packed edge: bits 0-15 = src, bits 16-23 = dst & 255.

__global__ __launch_bounds__(256) void prep_k(
    const int* __restrict__ src, const int* __restrict__ dst,
    int* __restrict__ gcur, unsigned* __restrict__ binned,
    const float* __restrict__ x, _Float16* __restrict__ xh,
    const float* __restrict__ Wl1, const float* __restrict__ Wr1,
    const float* __restrict__ Wl2, const float* __restrict__ Wr2,
    const float* __restrict__ Wl3, const float* __restrict__ Wr3,
    _Float16* ph_l1, _Float16* pl_l1, _Float16* ph_r1, _Float16* pl_r1,
    _Float16* ph_c2, _Float16* pl_c2, _Float16* ph_l3, _Float16* pl_l3,
    _Float16* ph_r3, _Float16* pl_r3) {
  int blk = blockIdx.x;
  int t = threadIdx.x;
  if (blk < EBLKS) {
    __shared__ int h[BUCKETS];
    __shared__ int base[BUCKETS];
    for (int i = t; i < BUCKETS; i += 256) h[i] = 0;
    __syncthreads();
    int e0 = blk * ECHUNK;
    int eend = e0 + ECHUNK < N_EDGES ? e0 + ECHUNK : N_EDGES;
    for (int e = e0 + t; e < eend; e += 256) atomicAdd(&h[dst[e] >> 8], 1);
    __syncthreads();
    for (int i = t; i < BUCKETS; i += 256) {
      if (h[i]) base[i] = atomicAdd(&gcur[i], h[i]);
      h[i] = 0;  // reuse as local rank cursor
    }
    __syncthreads();
    for (int e = e0 + t; e < eend; e += 256) {
      int d = dst[e];
      int b = d >> 8;
      int r = atomicAdd(&h[b], 1);
      binned[(size_t)b * BCAP + base[b] + r] =
          (unsigned)src[e] | ((unsigned)(d & 255) << 16);
    }
  } else if (blk < EBLKS + 32) {
    // wprep: ph[((kb*128 + n)*4 + lq)*8 + j] = W[n][kb*32 + lq*8 + j]
    int g = (blk - EBLKS) * 256 + t;  // 0..8191
    const float *S0, *S1 = nullptr;
    _Float16 *ph, *pl;
    int f, K;
    if (g < 2048)      { f = g;        ph = ph_l1; pl = pl_l1; S0 = Wl1; K = 128; }
    else if (g < 4096) { f = g - 2048; ph = ph_r1; pl = pl_r1; S0 = Wr1; K = 128; }
    else if (g < 6144) { f = g - 4096; ph = ph_c2; pl = pl_c2; S0 = Wl2; S1 = Wr2; K = 128; }
    else if (g < 7168) { f = g - 6144; ph = ph_l3; pl = pl_l3; S0 = Wl3; K = 64; }
    else               { f = g - 7168; ph = ph_r3; pl = pl_r3; S0 = Wr3; K = 64; }
    int kb = f >> 9;
    int rem = f & 511;
    int n = rem >> 2;
    int lq = rem & 3;
    const float* srow =
        (S1 && n >= 64) ? (S1 + (size_t)(n - 64) * K) : (S0 + (size_t)n * K);
    int kbase = kb * 32 + lq * 8;
#pragma unroll
    for (int j = 0; j < 8; ++j) {
      float v = srow[kbase + j];
      _Float16 hi = (_Float16)v;
      ph[f * 8 + j] = hi;
      pl[f * 8 + j] = (_Float16)(v - (float)hi);
    }
  } else {
    int i = (blk - EBLKS - 32) * 256 + t;  // half8 group, 800000 total
    if (i >= N_NODES * 16) return;
    const float4* xp = (const float4*)x;
    float4 a = xp[2 * i];
    float4 b = xp[2 * i + 1];
    half8 hh;
    hh[0] = (_Float16)a.x; hh[1] = (_Float16)a.y; hh[2] = (_Float16)a.z; hh[3] = (_Float16)a.w;
    hh[4] = (_Float16)b.x; hh[5] = (_Float16)b.y; hh[6] = (_Float16)b.z; hh[7] = (_Float16)b.w;
    ((half8*)xh)[i] = hh;
  }
}

// One block per bucket: per-node offs/deg, node-grouped ushort csr; L2-local writes.
__global__ __launch_bounds__(256) void bucket_fill_k(const unsigned* __restrict__ binned,
                                                     const int* __restrict__ gcnt,
                                                     int* __restrict__ offs,
                                                     int* __restrict__ deg,
                                                     unsigned short* __restrict__ csr) {
  __shared__ int cnt[256];
  __shared__ int loc[256];
  __shared__ int cur[256];
  int b = blockIdx.x;
  int t = threadIdx.x;
  int base = b * BCAP;
  int end = base + gcnt[b];
  cnt[t] = 0;
  __syncthreads();
  for (int e = base + t; e < end; e += 256) atomicAdd(&cnt[(binned[e] >> 16) & 255], 1);
  __syncthreads();
  loc[t] = cnt[t];
  __syncthreads();
  for (int o = 1; o < 256; o <<= 1) {
    int v = (t >= o) ? loc[t - o] : 0;
    __syncthreads();
    loc[t] += v;
    __syncthreads();
  }
  int excl = loc[t] - cnt[t];
  int node = b * 256 + t;
  if (node < N_NODES) {
    offs[node] = base + excl;
    deg[node] = cnt[t];
  }
  cur[t] = excl;
  __syncthreads();
  for (int e = base + t; e < end; e += 256) {
    unsigned r = binned[e];
    int dl = (r >> 16) & 255;
    int p = atomicAdd(&cur[dl], 1);
    csr[base + p] = (unsigned short)(r & 0xFFFF);
  }
}

// ---------------- standalone fp16 mean aggregation (layer 2) ----------------

template <int D, bool FUSE>
__global__ __launch_bounds__(256) void agg_f16_k(const _Float16* __restrict__ in,
                                                 _Float16* __restrict__ out,
                                                 const int* __restrict__ offs,
                                                 const int* __restrict__ deg,
                                                 const unsigned short* __restrict__ csr,
                                                 const float* __restrict__ bias,
                                                 const _Float16* __restrict__ addend) {
  constexpr int L = D / 8;
  constexpr int NPB = 256 / L;
  int node = blockIdx.x * NPB + threadIdx.x / L;
  int lane = threadIdx.x & (L - 1);
  if (node >= N_NODES) return;
  int start = offs[node];
  int d = deg[node];
  const half8* ip = (const half8*)in;
  float acc[8];
#pragma unroll
  for (int j = 0; j < 8; ++j) acc[j] = 0.f;
  int e = 0;
  for (; e + 8 <= d; e += 8) {
    int s[8];
#pragma unroll
    for (int j = 0; j < 8; ++j) s[j] = csr[start + e + j];
    half8 v[8];
#pragma unroll
    for (int j = 0; j < 8; ++j) v[j] = ip[(size_t)s[j] * L + lane];
#pragma unroll
    for (int j = 0; j < 8; ++j)
#pragma unroll
      for (int q = 0; q < 8; ++q) acc[q] += (float)v[j][q];
  }
  for (; e + 4 <= d; e += 4) {
    int s[4];
#pragma unroll
    for (int j = 0; j < 4; ++j) s[j] = csr[start + e + j];
    half8 v[4];
#pragma unroll
    for (int j = 0; j < 4; ++j) v[j] = ip[(size_t)s[j] * L + lane];
#pragma unroll
    for (int j = 0; j < 4; ++j)
#pragma unroll
      for (int q = 0; q < 8; ++q) acc[q] += (float)v[j][q];
  }
  for (; e < d; ++e) {
    half8 v0 = ip[(size_t)csr[start + e] * L + lane];
#pragma unroll
    for (int q = 0; q < 8; ++q) acc[q] += (float)v0[q];
  }
  float inv = d > 0 ? 1.0f / (float)d : 0.0f;
  half8 o;
  if constexpr (FUSE) {
    half8 av = ((const half8*)addend)[(size_t)node * L + lane];
#pragma unroll
    for (int q = 0; q < 8; ++q)
      o[q] = (_Float16)(acc[q] * inv + bias[lane * 8 + q] + (float)av[q]);
  } else {
#pragma unroll
    for (int q = 0; q < 8; ++q) o[q] = (_Float16)(acc[q] * inv);
  }
  ((half8*)out)[(size_t)node * L + lane] = o;
}

// ---------------- fused agg + dual GEMM (layers 1 and 3), ITER=1 / high occupancy ----
// NB nodes per block with NB == 256/(K/8): every lane-group aggregates exactly one
// node (no serial node loop), then 4 waves split the NB x 128 output.
// C = mean@Wl^T + resid@Wr^T + bias. W packed hi/lo fp16 (2 MFMAs per tile).

template <int K, int NB, bool OUT32>
__global__ __launch_bounds__(256, 8) void fused_agg_gemm_k(
    const _Float16* __restrict__ feat,  // gather + residual source, K-wide rows
    const int* __restrict__ offs, const int* __restrict__ deg,
    const unsigned short* __restrict__ csr,
    const _Float16* __restrict__ Wlh, const _Float16* __restrict__ Wll,
    const _Float16* __restrict__ Wrh, const _Float16* __restrict__ Wrl,
    const float* __restrict__ bias, _Float16* __restrict__ C16,
    float* __restrict__ C32) {
  constexpr int L = K / 8;         // lanes per node in agg phase
  static_assert(256 / L == NB, "one lane-group per node");
  constexpr int STRIDE = K + 8;    // fp16 elems; pad balances LDS banks
  constexpr int KB = K / 32;
  constexpr int ROWG = NB / 16;    // row groups of 16
  constexpr int WPR = 4 / ROWG;    // waves per row group
  constexpr int CT = 8 / WPR;      // 16-col tiles per wave
  __shared__ _Float16 Asm[NB * STRIDE];
  int t = threadIdx.x;
  int base = blockIdx.x * NB;
  const half8* ip = (const half8*)feat;
  {
    int lane = t & (L - 1);
    int slot = t / L;              // 0..NB-1
    int node = base + slot;
    float acc[8];
#pragma unroll
    for (int j = 0; j < 8; ++j) acc[j] = 0.f;
    float inv = 0.f;
    if (node < N_NODES) {
      int start = offs[node];
      int d = deg[node];
      int e = 0;
      for (; e + 8 <= d; e += 8) {
        int s[8];
#pragma unroll
        for (int j = 0; j < 8; ++j) s[j] = csr[start + e + j];
        half8 v[8];
#pragma unroll
        for (int j = 0; j < 8; ++j) v[j] = ip[(size_t)s[j] * L + lane];
#pragma unroll
        for (int j = 0; j < 8; ++j)
#pragma unroll
          for (int q = 0; q < 8; ++q) acc[q] += (float)v[j][q];
      }
      for (; e + 4 <= d; e += 4) {
        int s[4];
#pragma unroll
        for (int j = 0; j < 4; ++j) s[j] = csr[start + e + j];
        half8 v[4];
#pragma unroll
        for (int j = 0; j < 4; ++j) v[j] = ip[(size_t)s[j] * L + lane];
#pragma unroll
        for (int j = 0; j < 4; ++j)
#pragma unroll
          for (int q = 0; q < 8; ++q) acc[q] += (float)v[j][q];
      }
      for (; e < d; ++e) {
        half8 v0 = ip[(size_t)csr[start + e] * L + lane];
#pragma unroll
        for (int q = 0; q < 8; ++q) acc[q] += (float)v0[q];
      }
      inv = d > 0 ? 1.0f / (float)d : 0.0f;
    }
    half8 o;
#pragma unroll
    for (int q = 0; q < 8; ++q) o[q] = (_Float16)(acc[q] * inv);
    *(half8*)&Asm[slot * STRIDE + lane * 8] = o;
  }
  __syncthreads();
  // ---- GEMM phase: wave -> (row group, col group)
  int wave = t >> 6;
  int lane = t & 63;
  int l15 = lane & 15;
  int lq = lane >> 4;
  int rowg = wave / WPR;
  int colbase = (wave % WPR) * (CT * 16);
  int row0 = base + rowg * 16;
  const int woff = (l15 * 4 + lq) * 8;
  f32x4 acc[CT];
#pragma unroll
  for (int c = 0; c < CT; ++c) acc[c] = (f32x4){0.f, 0.f, 0.f, 0.f};
  {  // op0: A = LDS mean rows, W = Wl
    const _Float16* asrc = &Asm[(rowg * 16 + l15) * STRIDE + lq * 8];
    half8 af[KB];
#pragma unroll
    for (int kb = 0; kb < KB; ++kb) af[kb] = *(const half8*)(asrc + kb * 32);
#pragma unroll
    for (int kb = 0; kb < KB; ++kb) {
#pragma unroll
      for (int ct = 0; ct < CT; ++ct) {
        size_t bi = (size_t)(kb * 128 + colbase + ct * 16) * 32 + woff;
        half8 bh = *(const half8*)(Wlh + bi);
        half8 bl = *(const half8*)(Wll + bi);
        acc[ct] = __builtin_amdgcn_mfma_f32_16x16x32_f16(af[kb], bh, acc[ct], 0, 0, 0);
        acc[ct] = __builtin_amdgcn_mfma_f32_16x16x32_f16(af[kb], bl, acc[ct], 0, 0, 0);
      }
    }
  }
  {  // op1: A = residual rows from global, W = Wr
    int arow = row0 + l15;
    if (arow >= N_NODES) arow = N_NODES - 1;
    const _Float16* ab = feat + (size_t)arow * K + lq * 8;
    half8 af[KB];
#pragma unroll
    for (int kb = 0; kb < KB; ++kb) af[kb] = *(const half8*)(ab + kb * 32);
#pragma unroll
    for (int kb = 0; kb < KB; ++kb) {
#pragma unroll
      for (int ct = 0; ct < CT; ++ct) {
        size_t bi = (size_t)(kb * 128 + colbase + ct * 16) * 32 + woff;
        half8 bh = *(const half8*)(Wrh + bi);
        half8 bl = *(const half8*)(Wrl + bi);
        acc[ct] = __builtin_amdgcn_mfma_f32_16x16x32_f16(af[kb], bh, acc[ct], 0, 0, 0);
        acc[ct] = __builtin_amdgcn_mfma_f32_16x16x32_f16(af[kb], bl, acc[ct], 0, 0, 0);
      }
    }
  }
#pragma unroll
  for (int r = 0; r < 4; ++r) {
    int row = row0 + lq * 4 + r;
    if (row >= N_NODES) continue;
#pragma unroll
    for (int ct = 0; ct < CT; ++ct) {
      int col = colbase + ct * 16 + l15;
      float v = acc[ct][r] + bias[col];
      if constexpr (OUT32)
        C32[(size_t)row * 128 + col] = v;
      else
        C16[(size_t)row * 128 + col] = (_Float16)v;
    }
  }
}

// ---------------- layer-2 dual-output GEMM ----------------

template <int K, bool DUAL, bool SPLIT, bool OUT32>
__global__ __launch_bounds__(256, 2) void gemm_f16_k(
    const _Float16* __restrict__ A1, const _Float16* __restrict__ W1h,
    const _Float16* __restrict__ W1l,
    const _Float16* __restrict__ A2, const _Float16* __restrict__ W2h,
    const _Float16* __restrict__ W2l,
    const float* __restrict__ bias, _Float16* __restrict__ C16,
    float* __restrict__ C32, _Float16* __restrict__ O2) {
  int wave = threadIdx.x >> 6;
  int lane = threadIdx.x & 63;
  int l15 = lane & 15;
  int lq = lane >> 4;
  int rowblk = blockIdx.x >> 1;
  int colg = blockIdx.x & 1;
  int rg = rowblk * 4 + wave;
  if (rg >= N_NODES / 16) return;
  int row0 = rg << 4;
  constexpr int KB = K / 32;
  constexpr int NN = 128;
  const int woff = (l15 * 4 + lq) * 8;
  f32x4 acc[4];
#pragma unroll
  for (int c = 0; c < 4; ++c) acc[c] = (f32x4){0.f, 0.f, 0.f, 0.f};
  constexpr int NOP = DUAL ? 2 : 1;
#pragma unroll
  for (int op = 0; op < NOP; ++op) {
    const _Float16* A = op ? A2 : A1;
    const _Float16* Wh = op ? W2h : W1h;
    const _Float16* Wl = op ? W2l : W1l;
    const _Float16* ab = A + (size_t)(row0 + l15) * K + lq * 8;
    half8 af[KB];
#pragma unroll
    for (int kb = 0; kb < KB; ++kb) af[kb] = *(const half8*)(ab + kb * 32);
#pragma unroll
    for (int kb = 0; kb < KB; ++kb) {
#pragma unroll
      for (int ct = 0; ct < 4; ++ct) {
        int n0 = colg * 64 + ct * 16;
        size_t base = (size_t)(kb * NN + n0) * 32 + woff;
        half8 bh = *(const half8*)(Wh + base);
        half8 bl = *(const half8*)(Wl + base);
        acc[ct] = __builtin_amdgcn_mfma_f32_16x16x32_f16(af[kb], bh, acc[ct], 0, 0, 0);
        acc[ct] = __builtin_amdgcn_mfma_f32_16x16x32_f16(af[kb], bl, acc[ct], 0, 0, 0);
      }
    }
  }
#pragma unroll
  for (int r = 0; r < 4; ++r) {
    int row = row0 + lq * 4 + r;
#pragma unroll
    for (int ct = 0; ct < 4; ++ct) {
      int col = colg * 64 + ct * 16 + l15;
      float v = acc[ct][r];
      if constexpr (SPLIT) {
        if (col < 64)
          C16[(size_t)row * 64 + col] = (_Float16)v;
        else
          O2[(size_t)row * 64 + (col - 64)] = (_Float16)v;
      } else {
        v += bias[col];
        if constexpr (OUT32)
          C32[(size_t)row * 128 + col] = v;
        else
          C16[(size_t)row * 128 + col] = (_Float16)v;
      }
    }
  }
}

extern "C" void kernel_launch(void* const* d_in, const int* in_sizes, int n_in,
                              void* d_out, int out_size, void* d_ws, size_t ws_size,
                              hipStream_t stream) {
  const float* x   = (const float*)d_in[0];
  const int* ei    = (const int*)d_in[1];
  const float* Wl1 = (const float*)d_in[2];
  const float* b1  = (const float*)d_in[3];
  const float* Wr1 = (const float*)d_in[4];
  const float* Wl2 = (const float*)d_in[5];
  const float* b2  = (const float*)d_in[6];
  const float* Wr2 = (const float*)d_in[7];
  const float* Wl3 = (const float*)d_in[8];
  const float* b3  = (const float*)d_in[9];
  const float* Wr3 = (const float*)d_in[10];
  float* out = (float*)d_out;

  const int* src = ei;            // edge_index[0]
  const int* dst = ei + N_EDGES;  // edge_index[1]

  char* ws = (char*)d_ws;
  size_t off = 0;
  auto take = [&](size_t bytes) {
    void* p = ws + off;
    off += (bytes + 255) & ~(size_t)255;
    return p;
  };
  int* deg    = (int*)take((size_t)N_NODES * 4);
  int* offs   = (int*)take((size_t)N_NODES * 4);
  int* gcur   = (int*)take((size_t)BUCKETS * 4);
  unsigned* binned = (unsigned*)take((size_t)BUCKETS * BCAP * 4);
  unsigned short* csr = (unsigned short*)take((size_t)BUCKETS * BCAP * 2);
  _Float16* xh  = (_Float16*)take((size_t)N_NODES * 128 * 2);
  _Float16* h1h = (_Float16*)take((size_t)N_NODES * 128 * 2);
  _Float16* Ph  = (_Float16*)take((size_t)N_NODES * 64 * 2);
  _Float16* Rh  = (_Float16*)take((size_t)N_NODES * 64 * 2);
  _Float16* h2h = (_Float16*)take((size_t)N_NODES * 64 * 2);
  _Float16* ph_l1 = (_Float16*)take(16384 * 2);
  _Float16* pl_l1 = (_Float16*)take(16384 * 2);
  _Float16* ph_r1 = (_Float16*)take(16384 * 2);
  _Float16* pl_r1 = (_Float16*)take(16384 * 2);
  _Float16* ph_c2 = (_Float16*)take(16384 * 2);
  _Float16* pl_c2 = (_Float16*)take(16384 * 2);
  _Float16* ph_l3 = (_Float16*)take(8192 * 2);
  _Float16* pl_l3 = (_Float16*)take(8192 * 2);
  _Float16* ph_r3 = (_Float16*)take(8192 * 2);
  _Float16* pl_r3 = (_Float16*)take(8192 * 2);

  // CSR reservation counters must start at 0
  hipMemsetAsync(gcur, 0, (size_t)BUCKETS * 4, stream);

  // fused prep: binscatter (196 blocks) + wprep (32) + xcast (3125)
  prep_k<<<EBLKS + 32 + 3125, 256, 0, stream>>>(
      src, dst, gcur, binned, x, xh, Wl1, Wr1, Wl2, Wr2, Wl3, Wr3, ph_l1, pl_l1,
      ph_r1, pl_r1, ph_c2, pl_c2, ph_l3, pl_l3, ph_r3, pl_r3);
  bucket_fill_k<<<BUCKETS, 256, 0, stream>>>(binned, gcur, offs, deg, csr);

  // layer 1 fused (16 nodes/block): h1 = mean(x)@Wl1^T + x@Wr1^T + b1
  fused_agg_gemm_k<128, 16, false><<<3125, 256, 0, stream>>>(
      xh, offs, deg, csr, ph_l1, pl_l1, ph_r1, pl_r1, b1, h1h, nullptr);

  // layer 2: [P|R] = h1 @ [Wl2;Wr2]^T, then h2 = mean(P) + b2 + R
  gemm_f16_k<128, false, true, false><<<1564, 256, 0, stream>>>(
      h1h, ph_c2, pl_c2, nullptr, nullptr, nullptr, nullptr, Ph, nullptr, Rh);
  agg_f16_k<64, true><<<1563, 256, 0, stream>>>(Ph, h2h, offs, deg, csr, b2, Rh);

  // layer 3 fused (32 nodes/block): out = mean(h2)@Wl3^T + h2@Wr3^T + b3 (fp32)
  fused_agg_gemm_k<64, 32, true><<<1563, 256, 0, stream>>>(
      h2h, offs, deg, csr, ph_l3, pl_l3, ph_r3, pl_r3, b3, nullptr, out);
}

// Round 11
// 246.628 us; speedup vs baseline: 1.1154x; 1.1154x over previous
//
#include <hip/hip_runtime.h>

#define N_NODES 50000
#define N_EDGES 800000
#define BUCKETS 196   // ceil(N_NODES / 256)
#define ECHUNK 4096
#define EBLKS 196     // ceil(N_EDGES / ECHUNK)
#define BCAP 5120     // bucket capacity; mean 4096, sigma 64 -> 16 sigma headroom

typedef __attribute__((ext_vector_type(8))) _Float16 half8;
typedef __attribute__((ext_vector_type(4))) float f32x4;

// ---------------- fused prep: binscatter (196) + wprep (32) + xcast (3125) ----------------
// Bucket b = dst >> 8. Packed edge: bits 0-15 = src, bits 16-23 = dst & 255.

__global__ __launch_bounds__(256) void prep_k(
    const int* __restrict__ src, const int* __restrict__ dst,
    int* __restrict__ gcur, unsigned* __restrict__ binned,
    const float* __restrict__ x, _Float16* __restrict__ xh,
    const float* __restrict__ Wl1, const float* __restrict__ Wr1,
    const float* __restrict__ Wl2, const float* __restrict__ Wr2,
    const float* __restrict__ Wl3, const float* __restrict__ Wr3,
    _Float16* ph_l1, _Float16* pl_l1, _Float16* ph_r1, _Float16* pl_r1,
    _Float16* ph_c2, _Float16* pl_c2, _Float16* ph_l3, _Float16* pl_l3,
    _Float16* ph_r3, _Float16* pl_r3) {
  int blk = blockIdx.x;
  int t = threadIdx.x;
  if (blk < EBLKS) {
    __shared__ int h[BUCKETS];
    __shared__ int base[BUCKETS];
    for (int i = t; i < BUCKETS; i += 256) h[i] = 0;
    __syncthreads();
    int e0 = blk * ECHUNK;
    int eend = e0 + ECHUNK < N_EDGES ? e0 + ECHUNK : N_EDGES;
    for (int e = e0 + t; e < eend; e += 256) atomicAdd(&h[dst[e] >> 8], 1);
    __syncthreads();
    for (int i = t; i < BUCKETS; i += 256) {
      if (h[i]) base[i] = atomicAdd(&gcur[i], h[i]);
      h[i] = 0;  // reuse as local rank cursor
    }
    __syncthreads();
    for (int e = e0 + t; e < eend; e += 256) {
      int d = dst[e];
      int b = d >> 8;
      int r = atomicAdd(&h[b], 1);
      binned[(size_t)b * BCAP + base[b] + r] =
          (unsigned)src[e] | ((unsigned)(d & 255) << 16);
    }
  } else if (blk < EBLKS + 32) {
    // wprep: ph[((kb*128 + n)*4 + lq)*8 + j] = W[n][kb*32 + lq*8 + j]
    int g = (blk - EBLKS) * 256 + t;  // 0..8191
    const float *S0, *S1 = nullptr;
    _Float16 *ph, *pl;
    int f, K;
    if (g < 2048)      { f = g;        ph = ph_l1; pl = pl_l1; S0 = Wl1; K = 128; }
    else if (g < 4096) { f = g - 2048; ph = ph_r1; pl = pl_r1; S0 = Wr1; K = 128; }
    else if (g < 6144) { f = g - 4096; ph = ph_c2; pl = pl_c2; S0 = Wl2; S1 = Wr2; K = 128; }
    else if (g < 7168) { f = g - 6144; ph = ph_l3; pl = pl_l3; S0 = Wl3; K = 64; }
    else               { f = g - 7168; ph = ph_r3; pl = pl_r3; S0 = Wr3; K = 64; }
    int kb = f >> 9;
    int rem = f & 511;
    int n = rem >> 2;
    int lq = rem & 3;
    const float* srow =
        (S1 && n >= 64) ? (S1 + (size_t)(n - 64) * K) : (S0 + (size_t)n * K);
    int kbase = kb * 32 + lq * 8;
#pragma unroll
    for (int j = 0; j < 8; ++j) {
      float v = srow[kbase + j];
      _Float16 hi = (_Float16)v;
      ph[f * 8 + j] = hi;
      pl[f * 8 + j] = (_Float16)(v - (float)hi);
    }
  } else {
    int i = (blk - EBLKS - 32) * 256 + t;  // half8 group, 800000 total
    if (i >= N_NODES * 16) return;
    const float4* xp = (const float4*)x;
    float4 a = xp[2 * i];
    float4 b = xp[2 * i + 1];
    half8 hh;
    hh[0] = (_Float16)a.x; hh[1] = (_Float16)a.y; hh[2] = (_Float16)a.z; hh[3] = (_Float16)a.w;
    hh[4] = (_Float16)b.x; hh[5] = (_Float16)b.y; hh[6] = (_Float16)b.z; hh[7] = (_Float16)b.w;
    ((half8*)xh)[i] = hh;
  }
}

// One block per bucket: per-node offs/deg, node-grouped ushort csr; L2-local writes.
__global__ __launch_bounds__(256) void bucket_fill_k(const unsigned* __restrict__ binned,
                                                     const int* __restrict__ gcnt,
                                                     int* __restrict__ offs,
                                                     int* __restrict__ deg,
                                                     unsigned short* __restrict__ csr) {
  __shared__ int cnt[256];
  __shared__ int loc[256];
  __shared__ int cur[256];
  int b = blockIdx.x;
  int t = threadIdx.x;
  int base = b * BCAP;
  int end = base + gcnt[b];
  cnt[t] = 0;
  __syncthreads();
  for (int e = base + t; e < end; e += 256) atomicAdd(&cnt[(binned[e] >> 16) & 255], 1);
  __syncthreads();
  loc[t] = cnt[t];
  __syncthreads();
  for (int o = 1; o < 256; o <<= 1) {
    int v = (t >= o) ? loc[t - o] : 0;
    __syncthreads();
    loc[t] += v;
    __syncthreads();
  }
  int excl = loc[t] - cnt[t];
  int node = b * 256 + t;
  if (node < N_NODES) {
    offs[node] = base + excl;
    deg[node] = cnt[t];
  }
  cur[t] = excl;
  __syncthreads();
  for (int e = base + t; e < end; e += 256) {
    unsigned r = binned[e];
    int dl = (r >> 16) & 255;
    int p = atomicAdd(&cur[dl], 1);
    csr[base + p] = (unsigned short)(r & 0xFFFF);
  }
}

// ---------------- standalone fp16 mean aggregation (layer 2) ----------------

template <int D, bool FUSE>
__global__ __launch_bounds__(256) void agg_f16_k(const _Float16* __restrict__ in,
                                                 _Float16* __restrict__ out,
                                                 const int* __restrict__ offs,
                                                 const int* __restrict__ deg,
                                                 const unsigned short* __restrict__ csr,
                                                 const float* __restrict__ bias,
                                                 const _Float16* __restrict__ addend) {
  constexpr int L = D / 8;
  constexpr int NPB = 256 / L;
  int node = blockIdx.x * NPB + threadIdx.x / L;
  int lane = threadIdx.x & (L - 1);
  if (node >= N_NODES) return;
  int start = offs[node];
  int d = deg[node];
  const half8* ip = (const half8*)in;
  float acc[8];
#pragma unroll
  for (int j = 0; j < 8; ++j) acc[j] = 0.f;
  int e = 0;
  for (; e + 8 <= d; e += 8) {
    int s[8];
#pragma unroll
    for (int j = 0; j < 8; ++j) s[j] = csr[start + e + j];
    half8 v[8];
#pragma unroll
    for (int j = 0; j < 8; ++j) v[j] = ip[(size_t)s[j] * L + lane];
#pragma unroll
    for (int j = 0; j < 8; ++j)
#pragma unroll
      for (int q = 0; q < 8; ++q) acc[q] += (float)v[j][q];
  }
  for (; e + 4 <= d; e += 4) {
    int s[4];
#pragma unroll
    for (int j = 0; j < 4; ++j) s[j] = csr[start + e + j];
    half8 v[4];
#pragma unroll
    for (int j = 0; j < 4; ++j) v[j] = ip[(size_t)s[j] * L + lane];
#pragma unroll
    for (int j = 0; j < 4; ++j)
#pragma unroll
      for (int q = 0; q < 8; ++q) acc[q] += (float)v[j][q];
  }
  for (; e < d; ++e) {
    half8 v0 = ip[(size_t)csr[start + e] * L + lane];
#pragma unroll
    for (int q = 0; q < 8; ++q) acc[q] += (float)v0[q];
  }
  float inv = d > 0 ? 1.0f / (float)d : 0.0f;
  half8 o;
  if constexpr (FUSE) {
    half8 av = ((const half8*)addend)[(size_t)node * L + lane];
#pragma unroll
    for (int q = 0; q < 8; ++q)
      o[q] = (_Float16)(acc[q] * inv + bias[lane * 8 + q] + (float)av[q]);
  } else {
#pragma unroll
    for (int q = 0; q < 8; ++q) o[q] = (_Float16)(acc[q] * inv);
  }
  ((half8*)out)[(size_t)node * L + lane] = o;
}

// ---------------- fused agg + dual GEMM (layers 1 and 3) ----------------
// NB nodes per block, NB == 256/(K/8): each lane-group aggregates exactly one node,
// then 4 waves split the NB x 128 MFMA output.
// launch_bounds(256,4): 128 VGPR budget -- (256,8) caused scratch spills (round 10:
// VGPR=32, WRITE_SIZE 12.5->79 MB). Grid >= 1563 keeps >= 6 blocks/CU available.

template <int K, int NB, bool OUT32>
__global__ __launch_bounds__(256, 4) void fused_agg_gemm_k(
    const _Float16* __restrict__ feat,  // gather + residual source, K-wide rows
    const int* __restrict__ offs, const int* __restrict__ deg,
    const unsigned short* __restrict__ csr,
    const _Float16* __restrict__ Wlh, const _Float16* __restrict__ Wll,
    const _Float16* __restrict__ Wrh, const _Float16* __restrict__ Wrl,
    const float* __restrict__ bias, _Float16* __restrict__ C16,
    float* __restrict__ C32) {
  constexpr int L = K / 8;         // lanes per node in agg phase
  static_assert(256 / L == NB, "one lane-group per node");
  constexpr int STRIDE = K + 8;    // fp16 elems; pad balances LDS banks
  constexpr int KB = K / 32;
  constexpr int ROWG = NB / 16;    // row groups of 16
  constexpr int WPR = 4 / ROWG;    // waves per row group
  constexpr int CT = 8 / WPR;      // 16-col tiles per wave
  __shared__ _Float16 Asm[NB * STRIDE];
  int t = threadIdx.x;
  int base = blockIdx.x * NB;
  const half8* ip = (const half8*)feat;
  {
    int lane = t & (L - 1);
    int slot = t / L;              // 0..NB-1
    int node = base + slot;
    float acc[8];
#pragma unroll
    for (int j = 0; j < 8; ++j) acc[j] = 0.f;
    float inv = 0.f;
    if (node < N_NODES) {
      int start = offs[node];
      int d = deg[node];
      int e = 0;
      for (; e + 8 <= d; e += 8) {
        int s[8];
#pragma unroll
        for (int j = 0; j < 8; ++j) s[j] = csr[start + e + j];
        half8 v[8];
#pragma unroll
        for (int j = 0; j < 8; ++j) v[j] = ip[(size_t)s[j] * L + lane];
#pragma unroll
        for (int j = 0; j < 8; ++j)
#pragma unroll
          for (int q = 0; q < 8; ++q) acc[q] += (float)v[j][q];
      }
      for (; e + 4 <= d; e += 4) {
        int s[4];
#pragma unroll
        for (int j = 0; j < 4; ++j) s[j] = csr[start + e + j];
        half8 v[4];
#pragma unroll
        for (int j = 0; j < 4; ++j) v[j] = ip[(size_t)s[j] * L + lane];
#pragma unroll
        for (int j = 0; j < 4; ++j)
#pragma unroll
          for (int q = 0; q < 8; ++q) acc[q] += (float)v[j][q];
      }
      for (; e < d; ++e) {
        half8 v0 = ip[(size_t)csr[start + e] * L + lane];
#pragma unroll
        for (int q = 0; q < 8; ++q) acc[q] += (float)v0[q];
      }
      inv = d > 0 ? 1.0f / (float)d : 0.0f;
    }
    half8 o;
#pragma unroll
    for (int q = 0; q < 8; ++q) o[q] = (_Float16)(acc[q] * inv);
    *(half8*)&Asm[slot * STRIDE + lane * 8] = o;
  }
  __syncthreads();
  // ---- GEMM phase: wave -> (row group, col group)
  int wave = t >> 6;
  int lane = t & 63;
  int l15 = lane & 15;
  int lq = lane >> 4;
  int rowg = wave / WPR;
  int colbase = (wave % WPR) * (CT * 16);
  int row0 = base + rowg * 16;
  const int woff = (l15 * 4 + lq) * 8;
  f32x4 acc[CT];
#pragma unroll
  for (int c = 0; c < CT; ++c) acc[c] = (f32x4){0.f, 0.f, 0.f, 0.f};
  {  // op0: A = LDS mean rows, W = Wl
    const _Float16* asrc = &Asm[(rowg * 16 + l15) * STRIDE + lq * 8];
    half8 af[KB];
#pragma unroll
    for (int kb = 0; kb < KB; ++kb) af[kb] = *(const half8*)(asrc + kb * 32);
#pragma unroll
    for (int kb = 0; kb < KB; ++kb) {
#pragma unroll
      for (int ct = 0; ct < CT; ++ct) {
        size_t bi = (size_t)(kb * 128 + colbase + ct * 16) * 32 + woff;
        half8 bh = *(const half8*)(Wlh + bi);
        half8 bl = *(const half8*)(Wll + bi);
        acc[ct] = __builtin_amdgcn_mfma_f32_16x16x32_f16(af[kb], bh, acc[ct], 0, 0, 0);
        acc[ct] = __builtin_amdgcn_mfma_f32_16x16x32_f16(af[kb], bl, acc[ct], 0, 0, 0);
      }
    }
  }
  {  // op1: A = residual rows from global, W = Wr
    int arow = row0 + l15;
    if (arow >= N_NODES) arow = N_NODES - 1;
    const _Float16* ab = feat + (size_t)arow * K + lq * 8;
    half8 af[KB];
#pragma unroll
    for (int kb = 0; kb < KB; ++kb) af[kb] = *(const half8*)(ab + kb * 32);
#pragma unroll
    for (int kb = 0; kb < KB; ++kb) {
#pragma unroll
      for (int ct = 0; ct < CT; ++ct) {
        size_t bi = (size_t)(kb * 128 + colbase + ct * 16) * 32 + woff;
        half8 bh = *(const half8*)(Wrh + bi);
        half8 bl = *(const half8*)(Wrl + bi);
        acc[ct] = __builtin_amdgcn_mfma_f32_16x16x32_f16(af[kb], bh, acc[ct], 0, 0, 0);
        acc[ct] = __builtin_amdgcn_mfma_f32_16x16x32_f16(af[kb], bl, acc[ct], 0, 0, 0);
      }
    }
  }
#pragma unroll
  for (int r = 0; r < 4; ++r) {
    int row = row0 + lq * 4 + r;
    if (row >= N_NODES) continue;
#pragma unroll
    for (int ct = 0; ct < CT; ++ct) {
      int col = colbase + ct * 16 + l15;
      float v = acc[ct][r] + bias[col];
      if constexpr (OUT32)
        C32[(size_t)row * 128 + col] = v;
      else
        C16[(size_t)row * 128 + col] = (_Float16)v;
    }
  }
}

// ---------------- layer-2 dual-output GEMM ----------------

template <int K, bool DUAL, bool SPLIT, bool OUT32>
__global__ __launch_bounds__(256, 2) void gemm_f16_k(
    const _Float16* __restrict__ A1, const _Float16* __restrict__ W1h,
    const _Float16* __restrict__ W1l,
    const _Float16* __restrict__ A2, const _Float16* __restrict__ W2h,
    const _Float16* __restrict__ W2l,
    const float* __restrict__ bias, _Float16* __restrict__ C16,
    float* __restrict__ C32, _Float16* __restrict__ O2) {
  int wave = threadIdx.x >> 6;
  int lane = threadIdx.x & 63;
  int l15 = lane & 15;
  int lq = lane >> 4;
  int rowblk = blockIdx.x >> 1;
  int colg = blockIdx.x & 1;
  int rg = rowblk * 4 + wave;
  if (rg >= N_NODES / 16) return;
  int row0 = rg << 4;
  constexpr int KB = K / 32;
  constexpr int NN = 128;
  const int woff = (l15 * 4 + lq) * 8;
  f32x4 acc[4];
#pragma unroll
  for (int c = 0; c < 4; ++c) acc[c] = (f32x4){0.f, 0.f, 0.f, 0.f};
  constexpr int NOP = DUAL ? 2 : 1;
#pragma unroll
  for (int op = 0; op < NOP; ++op) {
    const _Float16* A = op ? A2 : A1;
    const _Float16* Wh = op ? W2h : W1h;
    const _Float16* Wl = op ? W2l : W1l;
    const _Float16* ab = A + (size_t)(row0 + l15) * K + lq * 8;
    half8 af[KB];
#pragma unroll
    for (int kb = 0; kb < KB; ++kb) af[kb] = *(const half8*)(ab + kb * 32);
#pragma unroll
    for (int kb = 0; kb < KB; ++kb) {
#pragma unroll
      for (int ct = 0; ct < 4; ++ct) {
        int n0 = colg * 64 + ct * 16;
        size_t base = (size_t)(kb * NN + n0) * 32 + woff;
        half8 bh = *(const half8*)(Wh + base);
        half8 bl = *(const half8*)(Wl + base);
        acc[ct] = __builtin_amdgcn_mfma_f32_16x16x32_f16(af[kb], bh, acc[ct], 0, 0, 0);
        acc[ct] = __builtin_amdgcn_mfma_f32_16x16x32_f16(af[kb], bl, acc[ct], 0, 0, 0);
      }
    }
  }
#pragma unroll
  for (int r = 0; r < 4; ++r) {
    int row = row0 + lq * 4 + r;
#pragma unroll
    for (int ct = 0; ct < 4; ++ct) {
      int col = colg * 64 + ct * 16 + l15;
      float v = acc[ct][r];
      if constexpr (SPLIT) {
        if (col < 64)
          C16[(size_t)row * 64 + col] = (_Float16)v;
        else
          O2[(size_t)row * 64 + (col - 64)] = (_Float16)v;
      } else {
        v += bias[col];
        if constexpr (OUT32)
          C32[(size_t)row * 128 + col] = v;
        else
          C16[(size_t)row * 128 + col] = (_Float16)v;
      }
    }
  }
}

extern "C" void kernel_launch(void* const* d_in, const int* in_sizes, int n_in,
                              void* d_out, int out_size, void* d_ws, size_t ws_size,
                              hipStream_t stream) {
  const float* x   = (const float*)d_in[0];
  const int* ei    = (const int*)d_in[1];
  const float* Wl1 = (const float*)d_in[2];
  const float* b1  = (const float*)d_in[3];
  const float* Wr1 = (const float*)d_in[4];
  const float* Wl2 = (const float*)d_in[5];
  const float* b2  = (const float*)d_in[6];
  const float* Wr2 = (const float*)d_in[7];
  const float* Wl3 = (const float*)d_in[8];
  const float* b3  = (const float*)d_in[9];
  const float* Wr3 = (const float*)d_in[10];
  float* out = (float*)d_out;

  const int* src = ei;            // edge_index[0]
  const int* dst = ei + N_EDGES;  // edge_index[1]

  char* ws = (char*)d_ws;
  size_t off = 0;
  auto take = [&](size_t bytes) {
    void* p = ws + off;
    off += (bytes + 255) & ~(size_t)255;
    return p;
  };
  int* deg    = (int*)take((size_t)N_NODES * 4);
  int* offs   = (int*)take((size_t)N_NODES * 4);
  int* gcur   = (int*)take((size_t)BUCKETS * 4);
  unsigned* binned = (unsigned*)take((size_t)BUCKETS * BCAP * 4);
  unsigned short* csr = (unsigned short*)take((size_t)BUCKETS * BCAP * 2);
  _Float16* xh  = (_Float16*)take((size_t)N_NODES * 128 * 2);
  _Float16* h1h = (_Float16*)take((size_t)N_NODES * 128 * 2);
  _Float16* Ph  = (_Float16*)take((size_t)N_NODES * 64 * 2);
  _Float16* Rh  = (_Float16*)take((size_t)N_NODES * 64 * 2);
  _Float16* h2h = (_Float16*)take((size_t)N_NODES * 64 * 2);
  _Float16* ph_l1 = (_Float16*)take(16384 * 2);
  _Float16* pl_l1 = (_Float16*)take(16384 * 2);
  _Float16* ph_r1 = (_Float16*)take(16384 * 2);
  _Float16* pl_r1 = (_Float16*)take(16384 * 2);
  _Float16* ph_c2 = (_Float16*)take(16384 * 2);
  _Float16* pl_c2 = (_Float16*)take(16384 * 2);
  _Float16* ph_l3 = (_Float16*)take(8192 * 2);
  _Float16* pl_l3 = (_Float16*)take(8192 * 2);
  _Float16* ph_r3 = (_Float16*)take(8192 * 2);
  _Float16* pl_r3 = (_Float16*)take(8192 * 2);

  // CSR reservation counters must start at 0
  hipMemsetAsync(gcur, 0, (size_t)BUCKETS * 4, stream);

  // fused prep: binscatter (196 blocks) + wprep (32) + xcast (3125)
  prep_k<<<EBLKS + 32 + 3125, 256, 0, stream>>>(
      src, dst, gcur, binned, x, xh, Wl1, Wr1, Wl2, Wr2, Wl3, Wr3, ph_l1, pl_l1,
      ph_r1, pl_r1, ph_c2, pl_c2, ph_l3, pl_l3, ph_r3, pl_r3);
  bucket_fill_k<<<BUCKETS, 256, 0, stream>>>(binned, gcur, offs, deg, csr);

  // layer 1 fused (16 nodes/block): h1 = mean(x)@Wl1^T + x@Wr1^T + b1
  fused_agg_gemm_k<128, 16, false><<<3125, 256, 0, stream>>>(
      xh, offs, deg, csr, ph_l1, pl_l1, ph_r1, pl_r1, b1, h1h, nullptr);

  // layer 2: [P|R] = h1 @ [Wl2;Wr2]^T, then h2 = mean(P) + b2 + R
  gemm_f16_k<128, false, true, false><<<1564, 256, 0, stream>>>(
      h1h, ph_c2, pl_c2, nullptr, nullptr, nullptr, nullptr, Ph, nullptr, Rh);
  agg_f16_k<64, true><<<1563, 256, 0, stream>>>(Ph, h2h, offs, deg, csr, b2, Rh);

  // layer 3 fused (32 nodes/block): out = mean(h2)@Wl3^T + h2@Wr3^T + b3 (fp32)
  fused_agg_gemm_k<64, 32, true><<<1563, 256, 0, stream>>>(
      h2h, offs, deg, csr, ph_l3, pl_l3, ph_r3, pl_r3, b3, nullptr, out);
}